// Round 3
// baseline (975.405 us; speedup 1.0000x reference)
//
#include <hip/hip_runtime.h>
#include <stdint.h>

#pragma clang fp contract(off)

#define BATCH 8
#define NANCH 200000
#define NGT   20
#define APT   8
#define CHUNK (256*APT)
#define NBLK  ((NANCH + CHUNK - 1)/CHUNK)
#define TCAP  4096
#define HALF_FLAT 800000u   // (BATCH*NANCH)/2 for the threefry odd/even split

struct Sel {
  uint32_t selR;   // 23-bit r threshold; 0xFFFFFFFF = keep all
  int32_t  selIdx; // index threshold among exact-r ties; 0x7FFFFFFF = all ties
  uint32_t need2;  // needs hist2 refinement
  uint32_t need3;  // needs tie index selection
  uint32_t bin1;
  uint32_t resid;
  uint32_t resid2;
  uint32_t tiecnt;
};

// ---- Threefry-2x32 (JAX-compatible, 20 rounds) ----
__device__ __forceinline__ void tf_round(uint32_t& x0, uint32_t& x1, int r) {
  x0 += x1; x1 = (x1 << r) | (x1 >> (32 - r)); x1 ^= x0;
}
__device__ __forceinline__ void threefry2x32(uint32_t k0, uint32_t k1,
                                             uint32_t x0, uint32_t x1,
                                             uint32_t& o0, uint32_t& o1) {
  uint32_t k2 = k0 ^ k1 ^ 0x1BD11BDAu;
  x0 += k0; x1 += k1;
  tf_round(x0,x1,13); tf_round(x0,x1,15); tf_round(x0,x1,26); tf_round(x0,x1,6);
  x0 += k1; x1 += k2 + 1u;
  tf_round(x0,x1,17); tf_round(x0,x1,29); tf_round(x0,x1,16); tf_round(x0,x1,24);
  x0 += k2; x1 += k0 + 2u;
  tf_round(x0,x1,13); tf_round(x0,x1,15); tf_round(x0,x1,26); tf_round(x0,x1,6);
  x0 += k0; x1 += k1 + 3u;
  tf_round(x0,x1,17); tf_round(x0,x1,29); tf_round(x0,x1,16); tf_round(x0,x1,24);
  x0 += k1; x1 += k2 + 4u;
  tf_round(x0,x1,13); tf_round(x0,x1,15); tf_round(x0,x1,26); tf_round(x0,x1,6);
  x0 += k2; x1 += k0 + 5u;
  o0 = x0; o1 = x1;
}
// Default (non-partitionable) JAX threefry split of key(42)=(0,42):
// counts=arange(4), halves x0=[0,1], x1=[2,3] -> enc(key,(0,2)), enc(key,(1,3));
// out = concat(o0s, o1s).reshape(2,2): kfg=(o0_a,o0_b), kbg=(o1_a,o1_b).
__device__ __forceinline__ void get_keys(uint32_t& f0, uint32_t& f1,
                                         uint32_t& g0, uint32_t& g1) {
  uint32_t a0,a1,b0,b1;
  threefry2x32(0u, 42u, 0u, 2u, a0, a1);
  threefry2x32(0u, 42u, 1u, 3u, b0, b1);
  f0 = a0; f1 = b0;   // kfg
  g0 = a1; g1 = b1;   // kbg
}
// uniform(key,(8,200000)) bits for flat f: threefry_2x32(key, arange(1.6M)) with
// odd/even halves: f<H -> o0 of enc(key,(f,f+H)); else o1 of enc(key,(f-H,f)).
// Return top-23 bits (bits>>9) — monotone-equivalent to the uniform float.
__device__ __forceinline__ uint32_t rbits23(uint32_t kk0, uint32_t kk1, uint32_t f) {
  uint32_t o0, o1;
  if (f < HALF_FLAT) { threefry2x32(kk0, kk1, f, f + HALF_FLAT, o0, o1); return o0 >> 9; }
  else               { threefry2x32(kk0, kk1, f - HALF_FLAT, f, o0, o1); return o1 >> 9; }
}

// ---- K1: gt_max[b][k] = max_n ov ----
__global__ __launch_bounds__(256) void k_gtmax(const float* __restrict__ gt,
                                               const float* __restrict__ anc,
                                               int* __restrict__ gtmax_bits) {
  __shared__ float sx1[NGT], sy1[NGT], sx2[NGT], sy2[NGT], sar[NGT];
  __shared__ int   sz[NGT];
  __shared__ int   smax[NGT];
  const int b = blockIdx.y, t = threadIdx.x;
  if (t < NGT) {
    const float* p = gt + (size_t)(b*NGT + t)*5;
    float x1=p[0], y1=p[1], x2=p[2], y2=p[3];
    float w = x2 - x1 + 1.0f, h = y2 - y1 + 1.0f;
    sx1[t]=x1; sy1[t]=y1; sx2[t]=x2; sy2[t]=y2; sar[t]=w*h;
    sz[t] = (w==1.0f) && (h==1.0f);
    smax[t] = 0; // bits of 0.0f; true max is always >= 0 with these inputs
  }
  __syncthreads();
  float tmax[NGT];
#pragma unroll
  for (int k=0;k<NGT;k++) tmax[k]=0.0f;
  const int base = blockIdx.x*CHUNK + t;
  const float4* a4 = (const float4*)anc;
  for (int j=0;j<APT;j++) {
    int n = base + j*256; if (n >= NANCH) break;
    float4 av = a4[n];
    float ax1=av.x, ay1=av.y, ax2=av.z, ay2=av.w;
    float aw = ax2-ax1+1.0f, ah = ay2-ay1+1.0f;
    float aarea = aw*ah;
    bool anz = (aw==1.0f)&&(ah==1.0f);
#pragma unroll
    for (int k=0;k<NGT;k++) {
      float iw = fminf(ax2, sx2[k]) - fmaxf(ax1, sx1[k]) + 1.0f;
      float ih = fminf(ay2, sy2[k]) - fmaxf(ay1, sy1[k]) + 1.0f;
      float inter = fmaxf(iw,0.0f)*fmaxf(ih,0.0f);
      float ov = inter / ((aarea + sar[k]) - inter);
      if (sz[k]) ov = 0.0f;
      if (anz)   ov = -1.0f;
      tmax[k] = fmaxf(tmax[k], ov);
    }
  }
#pragma unroll
  for (int k=0;k<NGT;k++) atomicMax(&smax[k], __float_as_int(tmax[k]));
  __syncthreads();
  if (t < NGT) atomicMax(&gtmax_bits[b*NGT + t], smax[t]);
}

// ---- K2: labels_pre (0:-1, 1:bg, 2:fg) + matches output (f32) ----
__global__ __launch_bounds__(256) void k_labels(const float* __restrict__ gt,
                                                const float* __restrict__ anc,
                                                const int* __restrict__ gtmax_bits,
                                                uint8_t* __restrict__ label_pre,
                                                float* __restrict__ out_matches) {
  __shared__ float sx1[NGT], sy1[NGT], sx2[NGT], sy2[NGT], sar[NGT], srep[NGT];
  __shared__ int   sz[NGT];
  const int b = blockIdx.y, t = threadIdx.x;
  if (t < NGT) {
    const float* p = gt + (size_t)(b*NGT + t)*5;
    float x1=p[0], y1=p[1], x2=p[2], y2=p[3];
    float w = x2 - x1 + 1.0f, h = y2 - y1 + 1.0f;
    sx1[t]=x1; sy1[t]=y1; sx2[t]=x2; sy2[t]=y2; sar[t]=w*h;
    sz[t] = (w==1.0f) && (h==1.0f);
    float m = __int_as_float(gtmax_bits[b*NGT + t]);
    srep[t] = (m == 0.0f) ? 1e-5f : m;   // ref: where(gt_max==0, 1e-5, gt_max)
  }
  __syncthreads();
  const int base = blockIdx.x*CHUNK + t;
  const float4* a4 = (const float4*)anc;
  for (int j=0;j<APT;j++) {
    int n = base + j*256; if (n >= NANCH) break;
    float4 av = a4[n];
    float ax1=av.x, ay1=av.y, ax2=av.z, ay2=av.w;
    float aw = ax2-ax1+1.0f, ah = ay2-ay1+1.0f;
    float aarea = aw*ah;
    bool anz = (aw==1.0f)&&(ah==1.0f);
    float best = -3.0f; int arg = 0; bool keep = false;
#pragma unroll
    for (int k=0;k<NGT;k++) {
      float iw = fminf(ax2, sx2[k]) - fmaxf(ax1, sx1[k]) + 1.0f;
      float ih = fminf(ay2, sy2[k]) - fmaxf(ay1, sy1[k]) + 1.0f;
      float inter = fmaxf(iw,0.0f)*fmaxf(ih,0.0f);
      float ov = inter / ((aarea + sar[k]) - inter);
      if (sz[k]) ov = 0.0f;
      if (anz)   ov = -1.0f;
      if (ov > best) { best = ov; arg = k; }   // first-occurrence argmax
      if (ov == srep[k]) keep = true;
    }
    uint8_t code = 0;
    if (best < 0.3f) code = 1;
    if (keep)        code = 2;
    if (best >= 0.7f) code = 2;
    label_pre[(size_t)b*NANCH + n] = code;
    out_matches[(size_t)b*NANCH + n] = (float)(arg + b*NGT);
  }
}

// ---- inds_inside + anchors passthrough (f32 in/out) ----
__global__ __launch_bounds__(256) void k_misc(const float* __restrict__ anc,
                                              float* __restrict__ out_inds,
                                              float* __restrict__ out_anc) {
  int i = blockIdx.x*blockDim.x + threadIdx.x;
  if (i < NANCH) out_inds[i] = (float)i;
  if (i < NANCH*4) out_anc[i] = anc[i];
}

// ---- S1: coarse histogram (top-10 bits of 23-bit r) for fg & bg ----
__global__ __launch_bounds__(256) void k_hist1(const uint8_t* __restrict__ label_pre,
                                               uint32_t* __restrict__ hist1) {
  __shared__ uint32_t h[2048];
  const int b = blockIdx.y, t = threadIdx.x;
  for (int i=t;i<2048;i+=256) h[i]=0;
  __syncthreads();
  uint32_t f0,f1,g0,g1; get_keys(f0,f1,g0,g1);
  const int base = blockIdx.x*CHUNK + t;
  for (int j=0;j<APT;j++) {
    int n = base + j*256; if (n >= NANCH) break;
    uint8_t lab = label_pre[(size_t)b*NANCH + n];
    if (lab == 2) {
      uint32_t rb = rbits23(f0,f1,(uint32_t)(b*NANCH+n));
      atomicAdd(&h[rb>>13], 1u);
    } else if (lab == 1) {
      uint32_t rb = rbits23(g0,g1,(uint32_t)(b*NANCH+n));
      atomicAdd(&h[1024 + (rb>>13)], 1u);
    }
  }
  __syncthreads();
  for (int i=t;i<2048;i+=256) { uint32_t v=h[i]; if (v) atomicAdd(&hist1[b*2048 + i], v); }
}

// ---- S2: pick coarse bin + residual rank per (batch, fg/bg) ----
__global__ void k_sel1(const uint32_t* __restrict__ hist1, Sel* __restrict__ sel) {
  __shared__ uint32_t cfg[BATCH];
  int t = threadIdx.x;
  if (t < BATCH) {
    uint32_t s = 0; const uint32_t* h = hist1 + t*2048;
    for (int i=0;i<1024;i++) s += h[i];
    cfg[t] = s;
  }
  __syncthreads();
  if (t < 16) {
    int b = t >> 1, m = t & 1;
    const uint32_t* h = hist1 + b*2048 + m*1024;
    uint32_t count, target;
    if (m == 0) { count = cfg[b]; target = 128u; }
    else {
      uint32_t s = 0; for (int i=0;i<1024;i++) s += h[i];
      count = s;
      uint32_t kept = cfg[b] < 128u ? cfg[b] : 128u;
      target = 256u - kept;                 // num_bg = 256 - kept_fg
    }
    Sel s; s.tiecnt = 0; s.resid2 = 0;
    if (count <= target) {
      s.selR = 0xFFFFFFFFu; s.selIdx = 0x7FFFFFFF; s.need2 = 0; s.need3 = 0;
      s.bin1 = 0; s.resid = 0;
    } else {
      uint32_t cum = 0, j = 0;
      for (j = 0; j < 1024u; j++) { if (cum + h[j] >= target) break; cum += h[j]; }
      s.bin1 = j; s.resid = target - cum; s.need2 = 1; s.need3 = 0;
      s.selR = 0; s.selIdx = 0x7FFFFFFF;
    }
    sel[t] = s;
  }
}

// ---- S3: fine histogram (low-13 bits) inside the chosen coarse bin ----
__global__ __launch_bounds__(256) void k_hist2(const uint8_t* __restrict__ label_pre,
                                               const Sel* __restrict__ sel,
                                               uint32_t* __restrict__ hist2) {
  const int b = blockIdx.y, t = threadIdx.x;
  __shared__ uint32_t nf, nb_, binf, binb;
  if (t == 0) {
    nf = sel[2*b].need2;   binf = sel[2*b].bin1;
    nb_ = sel[2*b+1].need2; binb = sel[2*b+1].bin1;
  }
  __syncthreads();
  if (!nf && !nb_) return;
  uint32_t f0,f1,g0,g1; get_keys(f0,f1,g0,g1);
  const int base = blockIdx.x*CHUNK + t;
  for (int j=0;j<APT;j++) {
    int n = base + j*256; if (n >= NANCH) break;
    uint8_t lab = label_pre[(size_t)b*NANCH + n];
    if (lab == 2 && nf) {
      uint32_t rb = rbits23(f0,f1,(uint32_t)(b*NANCH+n));
      if ((rb>>13) == binf) atomicAdd(&hist2[(2*b)*8192 + (rb & 8191u)], 1u);
    } else if (lab == 1 && nb_) {
      uint32_t rb = rbits23(g0,g1,(uint32_t)(b*NANCH+n));
      if ((rb>>13) == binb) atomicAdd(&hist2[(2*b+1)*8192 + (rb & 8191u)], 1u);
    }
  }
}

// ---- S4: exact r threshold; detect index-tie case ----
__global__ void k_sel2(const uint32_t* __restrict__ hist2, Sel* __restrict__ sel) {
  int t = threadIdx.x;
  if (t < 16 && sel[t].need2) {
    const uint32_t* h = hist2 + t*8192;
    uint32_t target = sel[t].resid;
    uint32_t cum = 0, j = 0;
    for (j = 0; j < 8192u; j++) { if (cum + h[j] >= target) break; cum += h[j]; }
    sel[t].selR = (sel[t].bin1 << 13) | j;
    uint32_t r2 = target - cum, tc = h[j];
    if (r2 == tc) { sel[t].selIdx = 0x7FFFFFFF; sel[t].need3 = 0; }
    else { sel[t].need3 = 1; sel[t].resid2 = r2; sel[t].tiecnt = 0; }
  }
}

// ---- S5: gather indices of exact-r ties ----
__global__ __launch_bounds__(256) void k_ties(const uint8_t* __restrict__ label_pre,
                                              Sel* __restrict__ sel,
                                              int* __restrict__ tiebuf) {
  const int b = blockIdx.y, t = threadIdx.x;
  __shared__ uint32_t nf, nb_, rF, rB;
  if (t == 0) {
    nf = sel[2*b].need3;   rF = sel[2*b].selR;
    nb_ = sel[2*b+1].need3; rB = sel[2*b+1].selR;
  }
  __syncthreads();
  if (!nf && !nb_) return;
  uint32_t f0,f1,g0,g1; get_keys(f0,f1,g0,g1);
  const int base = blockIdx.x*CHUNK + t;
  for (int j=0;j<APT;j++) {
    int n = base + j*256; if (n >= NANCH) break;
    uint8_t lab = label_pre[(size_t)b*NANCH + n];
    if (lab == 2 && nf) {
      uint32_t rb = rbits23(f0,f1,(uint32_t)(b*NANCH+n));
      if (rb == rF) { uint32_t p = atomicAdd(&sel[2*b].tiecnt,1u); if (p < TCAP) tiebuf[(2*b)*TCAP + p] = n; }
    } else if (lab == 1 && nb_) {
      uint32_t rb = rbits23(g0,g1,(uint32_t)(b*NANCH+n));
      if (rb == rB) { uint32_t p = atomicAdd(&sel[2*b+1].tiecnt,1u); if (p < TCAP) tiebuf[(2*b+1)*TCAP + p] = n; }
    }
  }
}

// ---- S6: resid2-th smallest index among ties (binary search) ----
__global__ __launch_bounds__(256) void k_selidx(Sel* __restrict__ sel,
                                                const int* __restrict__ tiebuf) {
  const int c = blockIdx.x;
  __shared__ int scnt;
  __shared__ uint32_t sneed;
  if (threadIdx.x == 0) sneed = sel[c].need3;
  __syncthreads();
  if (!sneed) return;
  uint32_t tcu = sel[c].tiecnt;
  int cnt = (int)(tcu < (uint32_t)TCAP ? tcu : (uint32_t)TCAP);
  int need = (int)sel[c].resid2;
  const int* tb = tiebuf + c*TCAP;
  int lo = 0, hi = NANCH - 1;
  while (lo < hi) {
    int mid = (lo + hi) >> 1;
    if (threadIdx.x == 0) scnt = 0;
    __syncthreads();
    int local = 0;
    for (int i = threadIdx.x; i < cnt; i += blockDim.x) if (tb[i] <= mid) local++;
    if (local) atomicAdd(&scnt, local);
    __syncthreads();
    if (scnt >= need) hi = mid; else lo = mid + 1;
    __syncthreads();
  }
  if (threadIdx.x == 0) sel[c].selIdx = lo;
}

// ---- K3: final labels (f32 out) ----
__global__ __launch_bounds__(256) void k_final(const uint8_t* __restrict__ label_pre,
                                               const Sel* __restrict__ sel,
                                               float* __restrict__ out_labels) {
  const int b = blockIdx.y, t = threadIdx.x;
  __shared__ uint32_t rF, rB; __shared__ int32_t iF, iB;
  if (t == 0) {
    rF = sel[2*b].selR;   iF = sel[2*b].selIdx;
    rB = sel[2*b+1].selR; iB = sel[2*b+1].selIdx;
  }
  __syncthreads();
  uint32_t f0,f1,g0,g1; get_keys(f0,f1,g0,g1);
  const int base = blockIdx.x*CHUNK + t;
  for (int j=0;j<APT;j++) {
    int n = base + j*256; if (n >= NANCH) break;
    uint8_t lab = label_pre[(size_t)b*NANCH + n];
    float o = -1.0f;
    if (lab == 1) {                            // bg candidate
      uint32_t rb = rbits23(g0,g1,(uint32_t)(b*NANCH+n));
      bool keep = (rb < rB) || (rb == rB && n <= iB);
      o = keep ? 0.0f : -1.0f;
    } else if (lab == 2) {                     // fg candidate
      uint32_t rb = rbits23(f0,f1,(uint32_t)(b*NANCH+n));
      bool keep = (rb < rF) || (rb == rF && n <= iF);
      o = keep ? 1.0f : -1.0f;
    }
    out_labels[(size_t)b*NANCH + n] = o;
  }
}

extern "C" void kernel_launch(void* const* d_in, const int* in_sizes, int n_in,
                              void* d_out, int out_size, void* d_ws, size_t ws_size,
                              hipStream_t stream) {
  const float* gt  = (const float*)d_in[1];   // gt_boxes (8,20,5) f32
  const float* anc = (const float*)d_in[4];   // anchors (1,200000,4) f32

  // d_out is FLOAT32. f32 element offsets:
  float* out         = (float*)d_out;
  float* out_labels  = out;                                  // [0, 1.6M)
  float* out_matches = out + (size_t)BATCH*NANCH;            // [1.6M, 3.2M)
  float* out_inds    = out + (size_t)2*BATCH*NANCH;          // [3.2M, 3.4M)
  float* out_anch    = out_inds + NANCH;                     // [3.4M, 4.2M)

  char* ws = (char*)d_ws;
  int*      gtmax  = (int*)(ws + 0);          // 8*20*4      = 640
  uint32_t* hist1  = (uint32_t*)(ws + 1024);  // 8*2048*4    = 65536
  uint32_t* hist2  = (uint32_t*)(ws + 66560); // 16*8192*4   = 524288
  Sel*      sel    = (Sel*)(ws + 590848);     // 16*32       = 512
  int*      tiebuf = (int*)(ws + 591360);     // 16*4096*4   = 262144
  uint8_t*  labpre = (uint8_t*)(ws + 853504); // 8*200000    = 1600000

  hipMemsetAsync(d_ws, 0, 591360, stream);    // zero gtmax + hist1 + hist2 + sel

  dim3 gB(NBLK, BATCH);
  k_gtmax <<<gB, 256, 0, stream>>>(gt, anc, gtmax);
  k_labels<<<gB, 256, 0, stream>>>(gt, anc, gtmax, labpre, out_matches);
  k_misc  <<<(NANCH*4 + 255)/256, 256, 0, stream>>>(anc, out_inds, out_anch);
  k_hist1 <<<gB, 256, 0, stream>>>(labpre, hist1);
  k_sel1  <<<1, 64, 0, stream>>>(hist1, sel);
  k_hist2 <<<gB, 256, 0, stream>>>(labpre, sel, hist2);
  k_sel2  <<<1, 64, 0, stream>>>(hist2, sel);
  k_ties  <<<gB, 256, 0, stream>>>(labpre, sel, tiebuf);
  k_selidx<<<16, 256, 0, stream>>>(sel, tiebuf);
  k_final <<<gB, 256, 0, stream>>>(labpre, sel, out_labels);
}

// Round 4
// 276.173 us; speedup vs baseline: 3.5319x; 3.5319x over previous
//
#include <hip/hip_runtime.h>
#include <stdint.h>

#pragma clang fp contract(off)

#define BATCH 8
#define NANCH 200000
#define NGT   20
#define APT   8
#define CHUNK (256*APT)
#define NBLK  ((NANCH + CHUNK - 1)/CHUNK)
#define TCAP  4096
#define HALF_FLAT 800000u   // (BATCH*NANCH)/2 for the threefry odd/even split

struct Sel {
  uint32_t selR;   // 23-bit r threshold; 0xFFFFFFFF = keep all
  int32_t  selIdx; // index threshold among exact-r ties; 0x7FFFFFFF = all ties
  uint32_t need2;  // needs hist2 refinement
  uint32_t need3;  // needs tie index selection
  uint32_t bin1;
  uint32_t resid;
  uint32_t resid2;
  uint32_t tiecnt;
};

// ---- Threefry-2x32 (JAX-compatible, 20 rounds) ----
__device__ __forceinline__ void tf_round(uint32_t& x0, uint32_t& x1, int r) {
  x0 += x1; x1 = (x1 << r) | (x1 >> (32 - r)); x1 ^= x0;
}
__device__ __forceinline__ void threefry2x32(uint32_t k0, uint32_t k1,
                                             uint32_t x0, uint32_t x1,
                                             uint32_t& o0, uint32_t& o1) {
  uint32_t k2 = k0 ^ k1 ^ 0x1BD11BDAu;
  x0 += k0; x1 += k1;
  tf_round(x0,x1,13); tf_round(x0,x1,15); tf_round(x0,x1,26); tf_round(x0,x1,6);
  x0 += k1; x1 += k2 + 1u;
  tf_round(x0,x1,17); tf_round(x0,x1,29); tf_round(x0,x1,16); tf_round(x0,x1,24);
  x0 += k2; x1 += k0 + 2u;
  tf_round(x0,x1,13); tf_round(x0,x1,15); tf_round(x0,x1,26); tf_round(x0,x1,6);
  x0 += k0; x1 += k1 + 3u;
  tf_round(x0,x1,17); tf_round(x0,x1,29); tf_round(x0,x1,16); tf_round(x0,x1,24);
  x0 += k1; x1 += k2 + 4u;
  tf_round(x0,x1,13); tf_round(x0,x1,15); tf_round(x0,x1,26); tf_round(x0,x1,6);
  x0 += k2; x1 += k0 + 5u;
  o0 = x0; o1 = x1;
}
// Default JAX threefry split of key(42)=(0,42): enc(key,(0,2)), enc(key,(1,3));
// kfg=(o0_a,o0_b), kbg=(o1_a,o1_b).
__device__ __forceinline__ void get_keys(uint32_t& f0, uint32_t& f1,
                                         uint32_t& g0, uint32_t& g1) {
  uint32_t a0,a1,b0,b1;
  threefry2x32(0u, 42u, 0u, 2u, a0, a1);
  threefry2x32(0u, 42u, 1u, 3u, b0, b1);
  f0 = a0; f1 = b0;   // kfg
  g0 = a1; g1 = b1;   // kbg
}
__device__ __forceinline__ uint32_t rbits23(uint32_t kk0, uint32_t kk1, uint32_t f) {
  uint32_t o0, o1;
  if (f < HALF_FLAT) { threefry2x32(kk0, kk1, f, f + HALF_FLAT, o0, o1); return o0 >> 9; }
  else               { threefry2x32(kk0, kk1, f - HALF_FLAT, f, o0, o1); return o1 >> 9; }
}

// ---- K1: gt_max[b][k] = max_n ov ----
__global__ __launch_bounds__(256) void k_gtmax(const float* __restrict__ gt,
                                               const float* __restrict__ anc,
                                               int* __restrict__ gtmax_bits) {
  __shared__ float sx1[NGT], sy1[NGT], sx2[NGT], sy2[NGT], sar[NGT];
  __shared__ int   sz[NGT];
  __shared__ int   smax[NGT];
  const int b = blockIdx.y, t = threadIdx.x;
  if (t < NGT) {
    const float* p = gt + (size_t)(b*NGT + t)*5;
    float x1=p[0], y1=p[1], x2=p[2], y2=p[3];
    float w = x2 - x1 + 1.0f, h = y2 - y1 + 1.0f;
    sx1[t]=x1; sy1[t]=y1; sx2[t]=x2; sy2[t]=y2; sar[t]=w*h;
    sz[t] = (w==1.0f) && (h==1.0f);
    smax[t] = 0;
  }
  __syncthreads();
  float tmax[NGT];
#pragma unroll
  for (int k=0;k<NGT;k++) tmax[k]=0.0f;
  const int base = blockIdx.x*CHUNK + t;
  const float4* a4 = (const float4*)anc;
  for (int j=0;j<APT;j++) {
    int n = base + j*256; if (n >= NANCH) break;
    float4 av = a4[n];
    float ax1=av.x, ay1=av.y, ax2=av.z, ay2=av.w;
    float aw = ax2-ax1+1.0f, ah = ay2-ay1+1.0f;
    float aarea = aw*ah;
    bool anz = (aw==1.0f)&&(ah==1.0f);
#pragma unroll
    for (int k=0;k<NGT;k++) {
      float iw = fminf(ax2, sx2[k]) - fmaxf(ax1, sx1[k]) + 1.0f;
      float ih = fminf(ay2, sy2[k]) - fmaxf(ay1, sy1[k]) + 1.0f;
      float inter = fmaxf(iw,0.0f)*fmaxf(ih,0.0f);
      float ov = inter / ((aarea + sar[k]) - inter);
      if (sz[k]) ov = 0.0f;
      if (anz)   ov = -1.0f;
      tmax[k] = fmaxf(tmax[k], ov);
    }
  }
#pragma unroll
  for (int k=0;k<NGT;k++) atomicMax(&smax[k], __float_as_int(tmax[k]));
  __syncthreads();
  if (t < NGT) atomicMax(&gtmax_bits[b*NGT + t], smax[t]);
}

// ---- K2: labels_pre (0:-1, 1:bg, 2:fg) + matches output (f32) ----
__global__ __launch_bounds__(256) void k_labels(const float* __restrict__ gt,
                                                const float* __restrict__ anc,
                                                const int* __restrict__ gtmax_bits,
                                                uint8_t* __restrict__ label_pre,
                                                float* __restrict__ out_matches) {
  __shared__ float sx1[NGT], sy1[NGT], sx2[NGT], sy2[NGT], sar[NGT], srep[NGT];
  __shared__ int   sz[NGT];
  const int b = blockIdx.y, t = threadIdx.x;
  if (t < NGT) {
    const float* p = gt + (size_t)(b*NGT + t)*5;
    float x1=p[0], y1=p[1], x2=p[2], y2=p[3];
    float w = x2 - x1 + 1.0f, h = y2 - y1 + 1.0f;
    sx1[t]=x1; sy1[t]=y1; sx2[t]=x2; sy2[t]=y2; sar[t]=w*h;
    sz[t] = (w==1.0f) && (h==1.0f);
    float m = __int_as_float(gtmax_bits[b*NGT + t]);
    srep[t] = (m == 0.0f) ? 1e-5f : m;
  }
  __syncthreads();
  const int base = blockIdx.x*CHUNK + t;
  const float4* a4 = (const float4*)anc;
  for (int j=0;j<APT;j++) {
    int n = base + j*256; if (n >= NANCH) break;
    float4 av = a4[n];
    float ax1=av.x, ay1=av.y, ax2=av.z, ay2=av.w;
    float aw = ax2-ax1+1.0f, ah = ay2-ay1+1.0f;
    float aarea = aw*ah;
    bool anz = (aw==1.0f)&&(ah==1.0f);
    float best = -3.0f; int arg = 0; bool keep = false;
#pragma unroll
    for (int k=0;k<NGT;k++) {
      float iw = fminf(ax2, sx2[k]) - fmaxf(ax1, sx1[k]) + 1.0f;
      float ih = fminf(ay2, sy2[k]) - fmaxf(ay1, sy1[k]) + 1.0f;
      float inter = fmaxf(iw,0.0f)*fmaxf(ih,0.0f);
      float ov = inter / ((aarea + sar[k]) - inter);
      if (sz[k]) ov = 0.0f;
      if (anz)   ov = -1.0f;
      if (ov > best) { best = ov; arg = k; }
      if (ov == srep[k]) keep = true;
    }
    uint8_t code = 0;
    if (best < 0.3f) code = 1;
    if (keep)        code = 2;
    if (best >= 0.7f) code = 2;
    label_pre[(size_t)b*NANCH + n] = code;
    out_matches[(size_t)b*NANCH + n] = (float)(arg + b*NGT);
  }
}

// ---- inds_inside + anchors passthrough ----
__global__ __launch_bounds__(256) void k_misc(const float* __restrict__ anc,
                                              float* __restrict__ out_inds,
                                              float* __restrict__ out_anc) {
  int i = blockIdx.x*blockDim.x + threadIdx.x;
  if (i < NANCH) out_inds[i] = (float)i;
  if (i < NANCH*4) out_anc[i] = anc[i];
}

// ---- S1: coarse histogram (top-10 bits of 23-bit r) for fg & bg ----
__global__ __launch_bounds__(256) void k_hist1(const uint8_t* __restrict__ label_pre,
                                               uint32_t* __restrict__ hist1) {
  __shared__ uint32_t h[2048];
  const int b = blockIdx.y, t = threadIdx.x;
  for (int i=t;i<2048;i+=256) h[i]=0;
  __syncthreads();
  uint32_t f0,f1,g0,g1; get_keys(f0,f1,g0,g1);
  const int base = blockIdx.x*CHUNK + t;
  for (int j=0;j<APT;j++) {
    int n = base + j*256; if (n >= NANCH) break;
    uint8_t lab = label_pre[(size_t)b*NANCH + n];
    if (lab == 2) {
      uint32_t rb = rbits23(f0,f1,(uint32_t)(b*NANCH+n));
      atomicAdd(&h[rb>>13], 1u);
    } else if (lab == 1) {
      uint32_t rb = rbits23(g0,g1,(uint32_t)(b*NANCH+n));
      atomicAdd(&h[1024 + (rb>>13)], 1u);
    }
  }
  __syncthreads();
  for (int i=t;i<2048;i+=256) { uint32_t v=h[i]; if (v) atomicAdd(&hist1[b*2048 + i], v); }
}

// ---- S2 (parallel): per-batch block; LDS prefix-scan over 1024 bins, fg then bg ----
__global__ __launch_bounds__(256) void k_sel1(const uint32_t* __restrict__ hist1,
                                              Sel* __restrict__ sel) {
  const int b = blockIdx.x, t = threadIdx.x;
  __shared__ uint32_t ls[256];
  __shared__ uint32_t s_keptfg;
  for (int m = 0; m < 2; m++) {
    const uint32_t* h = hist1 + b*2048 + m*1024;
    uint32_t loc[4]; uint32_t s = 0;
#pragma unroll
    for (int i=0;i<4;i++) { loc[i] = h[4*t+i]; s += loc[i]; }
    ls[t] = s; __syncthreads();
#pragma unroll
    for (int off=1; off<256; off<<=1) {
      uint32_t v = (t>=off) ? ls[t-off] : 0u; __syncthreads();
      ls[t] += v; __syncthreads();
    }
    uint32_t total = ls[255];
    uint32_t incl  = ls[t];
    uint32_t excl  = incl - s;
    uint32_t target = (m==0) ? 128u : (256u - s_keptfg);
    if (total <= target) {
      if (t == 0) {
        Sel so; so.selR=0xFFFFFFFFu; so.selIdx=0x7FFFFFFF; so.need2=0; so.need3=0;
        so.bin1=0; so.resid=0; so.resid2=0; so.tiecnt=0;
        sel[2*b+m] = so;
      }
    } else if (excl < target && target <= incl) {   // owner thread (unique)
      uint32_t cum = excl, j = 4*t, resid = 0;
#pragma unroll
      for (int i=0;i<4;i++) {
        if (cum + loc[i] >= target) { j = 4*t+i; resid = target - cum; break; }
        cum += loc[i];
      }
      Sel so; so.bin1=j; so.resid=resid; so.need2=1; so.need3=0;
      so.selR=0; so.selIdx=0x7FFFFFFF; so.resid2=0; so.tiecnt=0;
      sel[2*b+m] = so;
    }
    if (m == 0 && t == 0) s_keptfg = (total < 128u) ? total : 128u;
    __syncthreads();   // protect ls reuse + publish s_keptfg
  }
}

// ---- S3: fine histogram (low-13 bits) inside the chosen coarse bin ----
__global__ __launch_bounds__(256) void k_hist2(const uint8_t* __restrict__ label_pre,
                                               const Sel* __restrict__ sel,
                                               uint32_t* __restrict__ hist2) {
  const int b = blockIdx.y, t = threadIdx.x;
  __shared__ uint32_t nf, nb_, binf, binb;
  if (t == 0) {
    nf = sel[2*b].need2;   binf = sel[2*b].bin1;
    nb_ = sel[2*b+1].need2; binb = sel[2*b+1].bin1;
  }
  __syncthreads();
  if (!nf && !nb_) return;
  uint32_t f0,f1,g0,g1; get_keys(f0,f1,g0,g1);
  const int base = blockIdx.x*CHUNK + t;
  for (int j=0;j<APT;j++) {
    int n = base + j*256; if (n >= NANCH) break;
    uint8_t lab = label_pre[(size_t)b*NANCH + n];
    if (lab == 2 && nf) {
      uint32_t rb = rbits23(f0,f1,(uint32_t)(b*NANCH+n));
      if ((rb>>13) == binf) atomicAdd(&hist2[(2*b)*8192 + (rb & 8191u)], 1u);
    } else if (lab == 1 && nb_) {
      uint32_t rb = rbits23(g0,g1,(uint32_t)(b*NANCH+n));
      if ((rb>>13) == binb) atomicAdd(&hist2[(2*b+1)*8192 + (rb & 8191u)], 1u);
    }
  }
}

// ---- S4 (parallel): per-channel block; prefix-scan over 8192 fine bins ----
__global__ __launch_bounds__(256) void k_sel2(const uint32_t* __restrict__ hist2,
                                              Sel* __restrict__ sel) {
  const int c = blockIdx.x, t = threadIdx.x;
  __shared__ uint32_t ls[256];
  if (!sel[c].need2) return;
  const uint32_t* h = hist2 + c*8192;
  uint32_t loc[32]; uint32_t s = 0;
#pragma unroll
  for (int i=0;i<32;i++) { loc[i] = h[32*t+i]; s += loc[i]; }
  ls[t] = s; __syncthreads();
#pragma unroll
  for (int off=1; off<256; off<<=1) {
    uint32_t v = (t>=off) ? ls[t-off] : 0u; __syncthreads();
    ls[t] += v; __syncthreads();
  }
  uint32_t incl = ls[t], excl = incl - s;
  uint32_t target = sel[c].resid;
  if (excl < target && target <= incl) {   // unique owner (target>=1 guaranteed)
    uint32_t cum = excl, j = 32*t, hj = 0, resid = 0;
#pragma unroll
    for (int i=0;i<32;i++) {
      if (cum + loc[i] >= target) { j = 32*t+i; hj = loc[i]; resid = target - cum; break; }
      cum += loc[i];
    }
    sel[c].selR = (sel[c].bin1 << 13) | j;
    if (resid == hj) { sel[c].selIdx = 0x7FFFFFFF; sel[c].need3 = 0; }
    else { sel[c].need3 = 1; sel[c].resid2 = resid; sel[c].tiecnt = 0; }
  }
}

// ---- S5: gather indices of exact-r ties ----
__global__ __launch_bounds__(256) void k_ties(const uint8_t* __restrict__ label_pre,
                                              Sel* __restrict__ sel,
                                              int* __restrict__ tiebuf) {
  const int b = blockIdx.y, t = threadIdx.x;
  __shared__ uint32_t nf, nb_, rF, rB;
  if (t == 0) {
    nf = sel[2*b].need3;   rF = sel[2*b].selR;
    nb_ = sel[2*b+1].need3; rB = sel[2*b+1].selR;
  }
  __syncthreads();
  if (!nf && !nb_) return;
  uint32_t f0,f1,g0,g1; get_keys(f0,f1,g0,g1);
  const int base = blockIdx.x*CHUNK + t;
  for (int j=0;j<APT;j++) {
    int n = base + j*256; if (n >= NANCH) break;
    uint8_t lab = label_pre[(size_t)b*NANCH + n];
    if (lab == 2 && nf) {
      uint32_t rb = rbits23(f0,f1,(uint32_t)(b*NANCH+n));
      if (rb == rF) { uint32_t p = atomicAdd(&sel[2*b].tiecnt,1u); if (p < TCAP) tiebuf[(2*b)*TCAP + p] = n; }
    } else if (lab == 1 && nb_) {
      uint32_t rb = rbits23(g0,g1,(uint32_t)(b*NANCH+n));
      if (rb == rB) { uint32_t p = atomicAdd(&sel[2*b+1].tiecnt,1u); if (p < TCAP) tiebuf[(2*b+1)*TCAP + p] = n; }
    }
  }
}

// ---- S6: resid2-th smallest index among ties (binary search) ----
__global__ __launch_bounds__(256) void k_selidx(Sel* __restrict__ sel,
                                                const int* __restrict__ tiebuf) {
  const int c = blockIdx.x;
  __shared__ int scnt;
  __shared__ uint32_t sneed;
  if (threadIdx.x == 0) sneed = sel[c].need3;
  __syncthreads();
  if (!sneed) return;
  uint32_t tcu = sel[c].tiecnt;
  int cnt = (int)(tcu < (uint32_t)TCAP ? tcu : (uint32_t)TCAP);
  int need = (int)sel[c].resid2;
  const int* tb = tiebuf + c*TCAP;
  int lo = 0, hi = NANCH - 1;
  while (lo < hi) {
    int mid = (lo + hi) >> 1;
    if (threadIdx.x == 0) scnt = 0;
    __syncthreads();
    int local = 0;
    for (int i = threadIdx.x; i < cnt; i += blockDim.x) if (tb[i] <= mid) local++;
    if (local) atomicAdd(&scnt, local);
    __syncthreads();
    if (scnt >= need) hi = mid; else lo = mid + 1;
    __syncthreads();
  }
  if (threadIdx.x == 0) sel[c].selIdx = lo;
}

// ---- K3: final labels (f32 out) ----
__global__ __launch_bounds__(256) void k_final(const uint8_t* __restrict__ label_pre,
                                               const Sel* __restrict__ sel,
                                               float* __restrict__ out_labels) {
  const int b = blockIdx.y, t = threadIdx.x;
  __shared__ uint32_t rF, rB; __shared__ int32_t iF, iB;
  if (t == 0) {
    rF = sel[2*b].selR;   iF = sel[2*b].selIdx;
    rB = sel[2*b+1].selR; iB = sel[2*b+1].selIdx;
  }
  __syncthreads();
  uint32_t f0,f1,g0,g1; get_keys(f0,f1,g0,g1);
  const int base = blockIdx.x*CHUNK + t;
  for (int j=0;j<APT;j++) {
    int n = base + j*256; if (n >= NANCH) break;
    uint8_t lab = label_pre[(size_t)b*NANCH + n];
    float o = -1.0f;
    if (lab == 1) {
      uint32_t rb = rbits23(g0,g1,(uint32_t)(b*NANCH+n));
      bool keep = (rb < rB) || (rb == rB && n <= iB);
      o = keep ? 0.0f : -1.0f;
    } else if (lab == 2) {
      uint32_t rb = rbits23(f0,f1,(uint32_t)(b*NANCH+n));
      bool keep = (rb < rF) || (rb == rF && n <= iF);
      o = keep ? 1.0f : -1.0f;
    }
    out_labels[(size_t)b*NANCH + n] = o;
  }
}

extern "C" void kernel_launch(void* const* d_in, const int* in_sizes, int n_in,
                              void* d_out, int out_size, void* d_ws, size_t ws_size,
                              hipStream_t stream) {
  const float* gt  = (const float*)d_in[1];   // gt_boxes (8,20,5) f32
  const float* anc = (const float*)d_in[4];   // anchors (1,200000,4) f32

  float* out         = (float*)d_out;
  float* out_labels  = out;                                  // [0, 1.6M)
  float* out_matches = out + (size_t)BATCH*NANCH;            // [1.6M, 3.2M)
  float* out_inds    = out + (size_t)2*BATCH*NANCH;          // [3.2M, 3.4M)
  float* out_anch    = out_inds + NANCH;                     // [3.4M, 4.2M)

  char* ws = (char*)d_ws;
  int*      gtmax  = (int*)(ws + 0);          // 8*20*4      = 640
  uint32_t* hist1  = (uint32_t*)(ws + 1024);  // 8*2048*4    = 65536
  uint32_t* hist2  = (uint32_t*)(ws + 66560); // 16*8192*4   = 524288
  Sel*      sel    = (Sel*)(ws + 590848);     // 16*32       = 512
  int*      tiebuf = (int*)(ws + 591360);     // 16*4096*4   = 262144
  uint8_t*  labpre = (uint8_t*)(ws + 853504); // 8*200000    = 1600000

  hipMemsetAsync(d_ws, 0, 591360, stream);    // zero gtmax + hist1 + hist2 + sel

  dim3 gB(NBLK, BATCH);
  k_gtmax <<<gB, 256, 0, stream>>>(gt, anc, gtmax);
  k_labels<<<gB, 256, 0, stream>>>(gt, anc, gtmax, labpre, out_matches);
  k_misc  <<<(NANCH*4 + 255)/256, 256, 0, stream>>>(anc, out_inds, out_anch);
  k_hist1 <<<gB, 256, 0, stream>>>(labpre, hist1);
  k_sel1  <<<BATCH, 256, 0, stream>>>(hist1, sel);
  k_hist2 <<<gB, 256, 0, stream>>>(labpre, sel, hist2);
  k_sel2  <<<16, 256, 0, stream>>>(hist2, sel);
  k_ties  <<<gB, 256, 0, stream>>>(labpre, sel, tiebuf);
  k_selidx<<<16, 256, 0, stream>>>(sel, tiebuf);
  k_final <<<gB, 256, 0, stream>>>(labpre, sel, out_labels);
}

// Round 5
// 181.003 us; speedup vs baseline: 5.3889x; 1.5258x over previous
//
#include <hip/hip_runtime.h>
#include <stdint.h>

#pragma clang fp contract(off)

#define BATCH 8
#define NANCH 200000
#define NGT   20
#define APT   4
#define CHUNK (256*APT)                    // 1024
#define NBLK  ((NANCH + CHUNK - 1)/CHUNK)  // 196
#define HALF_FLAT 800000u                  // (BATCH*NANCH)/2 threefry split

struct Sel {
  uint32_t selR;   // 23-bit r threshold; 0xFFFFFFFF = keep all
  int32_t  selIdx; // unused (keep-all-ties semantics)
  uint32_t need2;
  uint32_t need3;  // unused
  uint32_t bin1;
  uint32_t resid;
  uint32_t resid2; // unused
  uint32_t tiecnt; // unused
};

// ---- Threefry-2x32 (JAX-compatible, 20 rounds) ----
__device__ __forceinline__ void tf_round(uint32_t& x0, uint32_t& x1, int r) {
  x0 += x1; x1 = (x1 << r) | (x1 >> (32 - r)); x1 ^= x0;
}
__device__ __forceinline__ void threefry2x32(uint32_t k0, uint32_t k1,
                                             uint32_t x0, uint32_t x1,
                                             uint32_t& o0, uint32_t& o1) {
  uint32_t k2 = k0 ^ k1 ^ 0x1BD11BDAu;
  x0 += k0; x1 += k1;
  tf_round(x0,x1,13); tf_round(x0,x1,15); tf_round(x0,x1,26); tf_round(x0,x1,6);
  x0 += k1; x1 += k2 + 1u;
  tf_round(x0,x1,17); tf_round(x0,x1,29); tf_round(x0,x1,16); tf_round(x0,x1,24);
  x0 += k2; x1 += k0 + 2u;
  tf_round(x0,x1,13); tf_round(x0,x1,15); tf_round(x0,x1,26); tf_round(x0,x1,6);
  x0 += k0; x1 += k1 + 3u;
  tf_round(x0,x1,17); tf_round(x0,x1,29); tf_round(x0,x1,16); tf_round(x0,x1,24);
  x0 += k1; x1 += k2 + 4u;
  tf_round(x0,x1,13); tf_round(x0,x1,15); tf_round(x0,x1,26); tf_round(x0,x1,6);
  x0 += k2; x1 += k0 + 5u;
  o0 = x0; o1 = x1;
}
__device__ __forceinline__ void get_keys(uint32_t& f0, uint32_t& f1,
                                         uint32_t& g0, uint32_t& g1) {
  uint32_t a0,a1,b0,b1;
  threefry2x32(0u, 42u, 0u, 2u, a0, a1);
  threefry2x32(0u, 42u, 1u, 3u, b0, b1);
  f0 = a0; f1 = b0;   // kfg
  g0 = a1; g1 = b1;   // kbg
}
__device__ __forceinline__ uint32_t rbits23(uint32_t kk0, uint32_t kk1, uint32_t f) {
  uint32_t o0, o1;
  if (f < HALF_FLAT) { threefry2x32(kk0, kk1, f, f + HALF_FLAT, o0, o1); return o0 >> 9; }
  else               { threefry2x32(kk0, kk1, f - HALF_FLAT, f, o0, o1); return o1 >> 9; }
}

// ov must be computed with the IDENTICAL expression in k_gtmax and k_labels
// (keep-test is exact equality between the two kernels' values).
__device__ __forceinline__ float iou_ov(float ax1,float ay1,float ax2,float ay2,
                                        float aarea, bool anz,
                                        float kx1,float ky1,float kx2,float ky2,
                                        float kar, bool kz) {
  float iw = fminf(ax2, kx2) - fmaxf(ax1, kx1) + 1.0f;
  float ih = fminf(ay2, ky2) - fmaxf(ay1, ky1) + 1.0f;
  float inter = fmaxf(iw,0.0f)*fmaxf(ih,0.0f);
  float denom = (aarea + kar) - inter;
  float ov = inter * __builtin_amdgcn_rcpf(denom);   // fast rcp (self-consistent)
  if (kz)  ov = 0.0f;
  if (anz) ov = -1.0f;
  return ov;
}

// ---- K_A: gt_max[b][k] = max_n ov (scalar gt constants, shuffle reduce) ----
__global__ __launch_bounds__(256) void k_gtmax(const float* __restrict__ gt,
                                               const float* __restrict__ anc,
                                               int* __restrict__ gtmax_bits) {
  const int b = blockIdx.y, t = threadIdx.x;
  const float* gp = gt + b*NGT*5;           // uniform -> s_load
  float kx1[NGT],ky1[NGT],kx2[NGT],ky2[NGT],kar[NGT];
  bool  kz[NGT];
#pragma unroll
  for (int k=0;k<NGT;k++) {
    float x1=gp[5*k], y1=gp[5*k+1], x2=gp[5*k+2], y2=gp[5*k+3];
    float w=x2-x1+1.0f, h=y2-y1+1.0f;
    kx1[k]=x1;ky1[k]=y1;kx2[k]=x2;ky2[k]=y2;kar[k]=w*h;
    kz[k]=(w==1.0f)&&(h==1.0f);
  }
  float tmax[NGT];
#pragma unroll
  for (int k=0;k<NGT;k++) tmax[k]=0.0f;
  const float4* a4 = (const float4*)anc;
  const int base = blockIdx.x*CHUNK + t;
#pragma unroll
  for (int j=0;j<APT;j++) {
    int n = base + j*256;
    bool valid = n < NANCH;
    float4 av = make_float4(0.f,0.f,0.f,0.f);
    if (valid) av = a4[n];
    float aw = av.z-av.x+1.0f, ah = av.w-av.y+1.0f;
    float aarea = aw*ah;
    bool anz = (aw==1.0f)&&(ah==1.0f);
#pragma unroll
    for (int k=0;k<NGT;k++) {
      float ov = iou_ov(av.x,av.y,av.z,av.w,aarea,anz,
                        kx1[k],ky1[k],kx2[k],ky2[k],kar[k],kz[k]);
      if (valid) tmax[k] = fmaxf(tmax[k], ov);
    }
  }
  __shared__ int smax[NGT];
  for (int i=t;i<NGT;i+=256) smax[i]=0;
  __syncthreads();
#pragma unroll
  for (int k=0;k<NGT;k++) {
    float v = tmax[k];
#pragma unroll
    for (int s=32;s>=1;s>>=1) v = fmaxf(v, __shfl_xor(v, s, 64));
    if ((t&63)==0) atomicMax(&smax[k], __float_as_int(v));
  }
  __syncthreads();
  if (t < NGT) atomicMax(&gtmax_bits[b*NGT + t], smax[t]);
}

// ---- K_B: labels_pre + matches + rb hash + hist1 + (b==0) inds/anchors ----
__global__ __launch_bounds__(256) void k_labels(const float* __restrict__ gt,
                                                const float* __restrict__ anc,
                                                const int* __restrict__ gtmax_bits,
                                                uint32_t* __restrict__ combo,
                                                float* __restrict__ out_matches,
                                                float* __restrict__ out_inds,
                                                float* __restrict__ out_anch,
                                                uint32_t* __restrict__ hist1) {
  const int b = blockIdx.y, t = threadIdx.x;
  const float* gp = gt + b*NGT*5;           // uniform -> s_load
  float kx1[NGT],ky1[NGT],kx2[NGT],ky2[NGT],kar[NGT],krep[NGT];
  bool  kz[NGT];
#pragma unroll
  for (int k=0;k<NGT;k++) {
    float x1=gp[5*k], y1=gp[5*k+1], x2=gp[5*k+2], y2=gp[5*k+3];
    float w=x2-x1+1.0f, h=y2-y1+1.0f;
    kx1[k]=x1;ky1[k]=y1;kx2[k]=x2;ky2[k]=y2;kar[k]=w*h;
    kz[k]=(w==1.0f)&&(h==1.0f);
    float m = __int_as_float(gtmax_bits[b*NGT + k]);
    krep[k] = (m == 0.0f) ? 1e-5f : m;
  }
  uint32_t f0,f1,g0,g1; get_keys(f0,f1,g0,g1);
  const float4* a4 = (const float4*)anc;
  float4* oa4 = (float4*)out_anch;
  const int base = blockIdx.x*CHUNK + t;
#pragma unroll
  for (int j=0;j<APT;j++) {
    int n = base + j*256;
    bool valid = n < NANCH;
    float4 av = make_float4(0.f,0.f,0.f,0.f);
    if (valid) av = a4[n];
    float aw = av.z-av.x+1.0f, ah = av.w-av.y+1.0f;
    float aarea = aw*ah;
    bool anz = (aw==1.0f)&&(ah==1.0f);
    float best = -3.0f; int arg = 0; bool keep = false;
#pragma unroll
    for (int k=0;k<NGT;k++) {
      float ov = iou_ov(av.x,av.y,av.z,av.w,aarea,anz,
                        kx1[k],ky1[k],kx2[k],ky2[k],kar[k],kz[k]);
      if (ov > best) { best = ov; arg = k; }      // first-occurrence argmax
      if (ov == krep[k]) keep = true;
    }
    uint32_t code = 0;
    if (best < 0.3f) code = 1;
    if (keep)        code = 2;
    if (best >= 0.7f) code = 2;
    if (valid) {
      uint32_t f = (uint32_t)(b*NANCH + n);
      uint32_t kk0 = (code==2)?f0:g0, kk1 = (code==2)?f1:g1;
      uint32_t rb = rbits23(kk0, kk1, f);
      combo[(size_t)b*NANCH + n] = (code<<30) | rb;
      out_matches[(size_t)b*NANCH + n] = (float)(arg + b*NGT);
      if (code) atomicAdd(&hist1[b*2048 + ((code==2)?0:1024) + (rb>>13)], 1u);
      if (b == 0) { out_inds[n] = (float)n; oa4[n] = av; }
    }
  }
}

// ---- K_C: per-batch block; LDS prefix-scan over 1024 coarse bins ----
__global__ __launch_bounds__(256) void k_sel1(const uint32_t* __restrict__ hist1,
                                              Sel* __restrict__ sel) {
  const int b = blockIdx.x, t = threadIdx.x;
  __shared__ uint32_t ls[256];
  __shared__ uint32_t s_keptfg;
  for (int m = 0; m < 2; m++) {
    const uint32_t* h = hist1 + b*2048 + m*1024;
    uint32_t loc[4]; uint32_t s = 0;
#pragma unroll
    for (int i=0;i<4;i++) { loc[i] = h[4*t+i]; s += loc[i]; }
    ls[t] = s; __syncthreads();
#pragma unroll
    for (int off=1; off<256; off<<=1) {
      uint32_t v = (t>=off) ? ls[t-off] : 0u; __syncthreads();
      ls[t] += v; __syncthreads();
    }
    uint32_t total = ls[255];
    uint32_t incl  = ls[t];
    uint32_t excl  = incl - s;
    uint32_t target = (m==0) ? 128u : (256u - s_keptfg);
    if (total <= target) {
      if (t == 0) {
        Sel so; so.selR=0xFFFFFFFFu; so.selIdx=0x7FFFFFFF; so.need2=0; so.need3=0;
        so.bin1=0; so.resid=0; so.resid2=0; so.tiecnt=0;
        sel[2*b+m] = so;
      }
    } else if (excl < target && target <= incl) {   // unique owner
      uint32_t cum = excl, j = 4*t, resid = 0;
#pragma unroll
      for (int i=0;i<4;i++) {
        if (cum + loc[i] >= target) { j = 4*t+i; resid = target - cum; break; }
        cum += loc[i];
      }
      Sel so; so.bin1=j; so.resid=resid; so.need2=1; so.need3=0;
      so.selR=0; so.selIdx=0x7FFFFFFF; so.resid2=0; so.tiecnt=0;
      sel[2*b+m] = so;
    }
    if (m == 0 && t == 0) s_keptfg = (total < 128u) ? total : 128u;
    __syncthreads();
  }
}

// ---- K_D: fine histogram from stored combo ----
__global__ __launch_bounds__(256) void k_hist2(const uint32_t* __restrict__ combo,
                                               const Sel* __restrict__ sel,
                                               uint32_t* __restrict__ hist2) {
  const int b = blockIdx.y, t = threadIdx.x;
  uint32_t nf = sel[2*b].need2,   binf = sel[2*b].bin1;
  uint32_t nb_ = sel[2*b+1].need2, binb = sel[2*b+1].bin1;
  if (!nf && !nb_) return;
  const int base = blockIdx.x*CHUNK + t;
#pragma unroll
  for (int j=0;j<APT;j++) {
    int n = base + j*256; if (n >= NANCH) break;
    uint32_t u = combo[(size_t)b*NANCH + n];
    uint32_t lab = u >> 30, rb = u & 0x7FFFFFu;
    if (lab == 2 && nf && (rb>>13) == binf)
      atomicAdd(&hist2[(2*b)*8192 + (rb & 8191u)], 1u);
    else if (lab == 1 && nb_ && (rb>>13) == binb)
      atomicAdd(&hist2[(2*b+1)*8192 + (rb & 8191u)], 1u);
  }
}

// ---- K_E: per-channel block; prefix-scan over 8192 fine bins ----
__global__ __launch_bounds__(256) void k_sel2(const uint32_t* __restrict__ hist2,
                                              Sel* __restrict__ sel) {
  const int c = blockIdx.x, t = threadIdx.x;
  __shared__ uint32_t ls[256];
  if (!sel[c].need2) return;
  const uint32_t* h = hist2 + c*8192;
  uint32_t loc[32]; uint32_t s = 0;
#pragma unroll
  for (int i=0;i<32;i++) { loc[i] = h[32*t+i]; s += loc[i]; }
  ls[t] = s; __syncthreads();
#pragma unroll
  for (int off=1; off<256; off<<=1) {
    uint32_t v = (t>=off) ? ls[t-off] : 0u; __syncthreads();
    ls[t] += v; __syncthreads();
  }
  uint32_t incl = ls[t], excl = incl - s;
  uint32_t target = sel[c].resid;
  if (excl < target && target <= incl) {   // unique owner (target>=1)
    uint32_t cum = excl, j = 32*t;
#pragma unroll
    for (int i=0;i<32;i++) {
      if (cum + loc[i] >= target) { j = 32*t+i; break; }
      cum += loc[i];
    }
    sel[c].selR = (sel[c].bin1 << 13) | j;   // keep all rb <= selR (ties kept)
  }
}

// ---- K_F: final labels from combo + thresholds ----
__global__ __launch_bounds__(256) void k_final(const uint32_t* __restrict__ combo,
                                               const Sel* __restrict__ sel,
                                               float* __restrict__ out_labels) {
  const int b = blockIdx.y, t = threadIdx.x;
  uint32_t rF = sel[2*b].selR, rB = sel[2*b+1].selR;
  const int base = blockIdx.x*CHUNK + t;
#pragma unroll
  for (int j=0;j<APT;j++) {
    int n = base + j*256; if (n >= NANCH) break;
    uint32_t u = combo[(size_t)b*NANCH + n];
    uint32_t lab = u >> 30, rb = u & 0x7FFFFFu;
    float o = -1.0f;
    if (lab == 1)      o = (rb <= rB) ? 0.0f : -1.0f;
    else if (lab == 2) o = (rb <= rF) ? 1.0f : -1.0f;
    out_labels[(size_t)b*NANCH + n] = o;
  }
}

extern "C" void kernel_launch(void* const* d_in, const int* in_sizes, int n_in,
                              void* d_out, int out_size, void* d_ws, size_t ws_size,
                              hipStream_t stream) {
  const float* gt  = (const float*)d_in[1];   // gt_boxes (8,20,5) f32
  const float* anc = (const float*)d_in[4];   // anchors (1,200000,4) f32

  float* out         = (float*)d_out;
  float* out_labels  = out;                                  // [0, 1.6M)
  float* out_matches = out + (size_t)BATCH*NANCH;            // [1.6M, 3.2M)
  float* out_inds    = out + (size_t)2*BATCH*NANCH;          // [3.2M, 3.4M)
  float* out_anch    = out_inds + NANCH;                     // [3.4M, 4.2M)

  char* ws = (char*)d_ws;
  int*      gtmax  = (int*)(ws + 0);          // 8*20*4    = 640   (pad 1KB)
  uint32_t* hist1  = (uint32_t*)(ws + 1024);  // 8*2048*4  = 64KB
  uint32_t* hist2  = (uint32_t*)(ws + 66560); // 16*8192*4 = 512KB
  Sel*      sel    = (Sel*)(ws + 590848);     // 16*32     = 512B
  uint32_t* combo  = (uint32_t*)(ws + 591360);// 1.6M*4    = 6.4MB

  hipMemsetAsync(d_ws, 0, 591360, stream);    // gtmax + hist1 + hist2 + sel

  dim3 gB(NBLK, BATCH);
  k_gtmax <<<gB, 256, 0, stream>>>(gt, anc, gtmax);
  k_labels<<<gB, 256, 0, stream>>>(gt, anc, gtmax, combo, out_matches,
                                   out_inds, out_anch, hist1);
  k_sel1  <<<BATCH, 256, 0, stream>>>(hist1, sel);
  k_hist2 <<<gB, 256, 0, stream>>>(combo, sel, hist2);
  k_sel2  <<<16, 256, 0, stream>>>(hist2, sel);
  k_final <<<gB, 256, 0, stream>>>(combo, sel, out_labels);
}

// Round 6
// 169.912 us; speedup vs baseline: 5.7406x; 1.0653x over previous
//
#include <hip/hip_runtime.h>
#include <stdint.h>

#pragma clang fp contract(off)

#define BATCH 8
#define NANCH 200000
#define NGT   20
#define APTG  8
#define CHUNKG (256*APTG)                    // 2048
#define NBLKG ((NANCH + CHUNKG - 1)/CHUNKG)  // 98
#define APTL  4
#define CHUNKL (256*APTL)                    // 1024
#define NBLKL ((NANCH + CHUNKL - 1)/CHUNKL)  // 196
#define HBITS 14
#define HBINS (1<<HBITS)                     // 16384
#define HALF_FLAT 800000u                    // (BATCH*NANCH)/2 threefry split

// ---- Threefry-2x32 (JAX-compatible, 20 rounds) ----
__device__ __forceinline__ void tf_round(uint32_t& x0, uint32_t& x1, int r) {
  x0 += x1; x1 = (x1 << r) | (x1 >> (32 - r)); x1 ^= x0;
}
__device__ __forceinline__ void threefry2x32(uint32_t k0, uint32_t k1,
                                             uint32_t x0, uint32_t x1,
                                             uint32_t& o0, uint32_t& o1) {
  uint32_t k2 = k0 ^ k1 ^ 0x1BD11BDAu;
  x0 += k0; x1 += k1;
  tf_round(x0,x1,13); tf_round(x0,x1,15); tf_round(x0,x1,26); tf_round(x0,x1,6);
  x0 += k1; x1 += k2 + 1u;
  tf_round(x0,x1,17); tf_round(x0,x1,29); tf_round(x0,x1,16); tf_round(x0,x1,24);
  x0 += k2; x1 += k0 + 2u;
  tf_round(x0,x1,13); tf_round(x0,x1,15); tf_round(x0,x1,26); tf_round(x0,x1,6);
  x0 += k0; x1 += k1 + 3u;
  tf_round(x0,x1,17); tf_round(x0,x1,29); tf_round(x0,x1,16); tf_round(x0,x1,24);
  x0 += k1; x1 += k2 + 4u;
  tf_round(x0,x1,13); tf_round(x0,x1,15); tf_round(x0,x1,26); tf_round(x0,x1,6);
  x0 += k2; x1 += k0 + 5u;
  o0 = x0; o1 = x1;
}
__device__ __forceinline__ void get_keys(uint32_t& f0, uint32_t& f1,
                                         uint32_t& g0, uint32_t& g1) {
  uint32_t a0,a1,b0,b1;
  threefry2x32(0u, 42u, 0u, 2u, a0, a1);
  threefry2x32(0u, 42u, 1u, 3u, b0, b1);
  f0 = a0; f1 = b0;   // kfg
  g0 = a1; g1 = b1;   // kbg
}
__device__ __forceinline__ uint32_t rbits23(uint32_t kk0, uint32_t kk1, uint32_t f) {
  uint32_t o0, o1;
  if (f < HALF_FLAT) { threefry2x32(kk0, kk1, f, f + HALF_FLAT, o0, o1); return o0 >> 9; }
  else               { threefry2x32(kk0, kk1, f - HALF_FLAT, f, o0, o1); return o1 >> 9; }
}

// IDENTICAL expression in k_gtmax and k_labels (keep-test is exact equality).
__device__ __forceinline__ float iou_ov(float ax1,float ay1,float ax2,float ay2,
                                        float aarea, bool anz,
                                        float kx1,float ky1,float kx2,float ky2,
                                        float kar, bool kz) {
  float iw = fminf(ax2, kx2) - fmaxf(ax1, kx1) + 1.0f;
  float ih = fminf(ay2, ky2) - fmaxf(ay1, ky1) + 1.0f;
  float inter = fmaxf(iw,0.0f)*fmaxf(ih,0.0f);
  float denom = (aarea + kar) - inter;
  float ov = inter * __builtin_amdgcn_rcpf(denom);
  if (kz)  ov = 0.0f;
  if (anz) ov = -1.0f;
  return ov;
}

// ---- K_A: gt_max[b][k] — k-outer, anchors in regs, shuffle reduce ----
__global__ __launch_bounds__(256, 8) void k_gtmax(const float* __restrict__ gt,
                                                  const float* __restrict__ anc,
                                                  int* __restrict__ gtmax_bits) {
  const int b = blockIdx.y, t = threadIdx.x;
  __shared__ float sx1[NGT], sy1[NGT], sx2[NGT], sy2[NGT], sar[NGT];
  __shared__ int   ssz[NGT];
  __shared__ int   smax[NGT];
  if (t < NGT) {
    const float* p = gt + (size_t)(b*NGT + t)*5;
    float x1=p[0], y1=p[1], x2=p[2], y2=p[3];
    float w = x2 - x1 + 1.0f, h = y2 - y1 + 1.0f;
    sx1[t]=x1; sy1[t]=y1; sx2[t]=x2; sy2[t]=y2; sar[t]=w*h;
    ssz[t] = (w==1.0f) && (h==1.0f);
    smax[t] = 0;
  }
  __syncthreads();
  const float4* a4 = (const float4*)anc;
  const int base = blockIdx.x*CHUNKG + t;
  float4 av[APTG]; float aarea[APTG]; bool anz[APTG];
#pragma unroll
  for (int j=0;j<APTG;j++) {
    int n = base + j*256; if (n > NANCH-1) n = NANCH-1;  // clamp: dup is max-neutral
    av[j] = a4[n];
    float aw = av[j].z-av[j].x+1.0f, ah = av[j].w-av[j].y+1.0f;
    aarea[j] = aw*ah;
    anz[j] = (aw==1.0f)&&(ah==1.0f);
  }
#pragma unroll 4
  for (int k=0;k<NGT;k++) {
    float kx1=sx1[k], ky1=sy1[k], kx2=sx2[k], ky2=sy2[k], kar=sar[k];
    bool kz = ssz[k];
    float tm = 0.0f;
#pragma unroll
    for (int j=0;j<APTG;j++)
      tm = fmaxf(tm, iou_ov(av[j].x,av[j].y,av[j].z,av[j].w,aarea[j],anz[j],
                            kx1,ky1,kx2,ky2,kar,kz));
#pragma unroll
    for (int s=32;s>=1;s>>=1) tm = fmaxf(tm, __shfl_xor(tm, s, 64));
    if ((t&63)==0) atomicMax(&smax[k], __float_as_int(tm));
  }
  __syncthreads();
  if (t < NGT) atomicMax(&gtmax_bits[b*NGT + t], smax[t]);
}

// ---- K_B: labels code + matches + rb hash + 14-bit histogram ----
__global__ __launch_bounds__(256, 8) void k_labels(const float* __restrict__ gt,
                                                   const float* __restrict__ anc,
                                                   const int* __restrict__ gtmax_bits,
                                                   uint32_t* __restrict__ combo,
                                                   float* __restrict__ out_matches,
                                                   uint32_t* __restrict__ hist) {
  const int b = blockIdx.y, t = threadIdx.x;
  __shared__ float sx1[NGT], sy1[NGT], sx2[NGT], sy2[NGT], sar[NGT], srep[NGT];
  __shared__ int   ssz[NGT];
  if (t < NGT) {
    const float* p = gt + (size_t)(b*NGT + t)*5;
    float x1=p[0], y1=p[1], x2=p[2], y2=p[3];
    float w = x2 - x1 + 1.0f, h = y2 - y1 + 1.0f;
    sx1[t]=x1; sy1[t]=y1; sx2[t]=x2; sy2[t]=y2; sar[t]=w*h;
    ssz[t] = (w==1.0f) && (h==1.0f);
    float m = __int_as_float(gtmax_bits[b*NGT + t]);
    srep[t] = (m == 0.0f) ? 1e-5f : m;
  }
  __syncthreads();
  const float4* a4 = (const float4*)anc;
  const int base = blockIdx.x*CHUNKL + t;
  float4 av[APTL]; float aarea[APTL]; bool anz[APTL]; bool valid[APTL];
#pragma unroll
  for (int j=0;j<APTL;j++) {
    int n = base + j*256;
    valid[j] = n < NANCH;
    if (n > NANCH-1) n = NANCH-1;
    av[j] = a4[n];
    float aw = av[j].z-av[j].x+1.0f, ah = av[j].w-av[j].y+1.0f;
    aarea[j] = aw*ah;
    anz[j] = (aw==1.0f)&&(ah==1.0f);
  }
  float best[APTL]; int arg[APTL]; uint32_t keep = 0;
#pragma unroll
  for (int j=0;j<APTL;j++) { best[j]=-3.0f; arg[j]=0; }
#pragma unroll 4
  for (int k=0;k<NGT;k++) {
    float kx1=sx1[k], ky1=sy1[k], kx2=sx2[k], ky2=sy2[k], kar=sar[k], krep=srep[k];
    bool kz = ssz[k];
#pragma unroll
    for (int j=0;j<APTL;j++) {
      float ov = iou_ov(av[j].x,av[j].y,av[j].z,av[j].w,aarea[j],anz[j],
                        kx1,ky1,kx2,ky2,kar,kz);
      if (ov > best[j]) { best[j] = ov; arg[j] = k; }  // first-occurrence argmax
      if (ov == krep) keep |= (1u<<j);
    }
  }
  uint32_t f0,f1,g0,g1; get_keys(f0,f1,g0,g1);
#pragma unroll
  for (int j=0;j<APTL;j++) {
    int n = base + j*256;
    if (!valid[j]) continue;
    uint32_t code = 0;
    if (best[j] < 0.3f) code = 1;
    if (keep & (1u<<j)) code = 2;
    if (best[j] >= 0.7f) code = 2;
    uint32_t f = (uint32_t)(b*NANCH + n);
    uint32_t kk0 = (code==2)?f0:g0, kk1 = (code==2)?f1:g1;
    uint32_t rb = rbits23(kk0, kk1, f);
    combo[(size_t)b*NANCH + n] = (code<<30) | rb;
    out_matches[(size_t)b*NANCH + n] = (float)(arg[j] + b*NGT);
    if (code) atomicAdd(&hist[b*2*HBINS + ((code==2)?0:HBINS) + (rb>>9)], 1u);
  }
}

// ---- K_C: per-batch selection over 14-bit hist (fg then bg) ----
__global__ __launch_bounds__(256) void k_sel(const uint32_t* __restrict__ hist,
                                             uint32_t* __restrict__ thr) {
  const int b = blockIdx.x, t = threadIdx.x;
  __shared__ uint32_t ls[256];
  __shared__ uint32_t s_keptfg;
  for (int m = 0; m < 2; m++) {
    const uint32_t* h = hist + b*2*HBINS + m*HBINS;   // 64 bins/thread
    uint32_t s = 0;
    for (int i=0;i<64;i++) s += h[64*t+i];
    ls[t] = s; __syncthreads();
#pragma unroll
    for (int off=1; off<256; off<<=1) {
      uint32_t v = (t>=off) ? ls[t-off] : 0u; __syncthreads();
      ls[t] += v; __syncthreads();
    }
    uint32_t total = ls[255];
    uint32_t incl  = ls[t], excl = incl - s;
    uint32_t target = (m==0) ? 128u : (256u - s_keptfg);
    if (total <= target) {
      if (t == 0) thr[2*b+m] = HBINS-1;               // keep all
    } else if (excl < target && target <= incl) {     // unique owner
      uint32_t cum = excl, j = 64*t;
      for (int i=0;i<64;i++) {
        uint32_t c = h[64*t+i];
        if (cum + c >= target) { j = 64*t+i; break; }
        cum += c;
      }
      thr[2*b+m] = j;                                  // keep rb14 <= j
    }
    if (m == 0 && t == 0) s_keptfg = (total < 128u) ? total : 128u;  // ref semantics
    __syncthreads();
  }
}

// ---- K_D: final labels + inds/anchors passthrough ----
__global__ __launch_bounds__(256) void k_final(const uint32_t* __restrict__ combo,
                                               const uint32_t* __restrict__ thr,
                                               const float* __restrict__ anc,
                                               float* __restrict__ out_labels,
                                               float* __restrict__ out_inds,
                                               float* __restrict__ out_anch) {
  const int b = blockIdx.y, t = threadIdx.x;
  uint32_t rF = thr[2*b], rB = thr[2*b+1];
  const float4* a4 = (const float4*)anc;
  float4* oa4 = (float4*)out_anch;
  const int base = blockIdx.x*CHUNKG + t;
#pragma unroll
  for (int j=0;j<APTG;j++) {
    int n = base + j*256; if (n >= NANCH) break;
    uint32_t u = combo[(size_t)b*NANCH + n];
    uint32_t lab = u >> 30, rb14 = (u & 0x7FFFFFu) >> 9;
    float o = -1.0f;
    if (lab == 1)      o = (rb14 <= rB) ? 0.0f : -1.0f;
    else if (lab == 2) o = (rb14 <= rF) ? 1.0f : -1.0f;
    out_labels[(size_t)b*NANCH + n] = o;
    if (b == 0) { out_inds[n] = (float)n; oa4[n] = a4[n]; }
  }
}

extern "C" void kernel_launch(void* const* d_in, const int* in_sizes, int n_in,
                              void* d_out, int out_size, void* d_ws, size_t ws_size,
                              hipStream_t stream) {
  const float* gt  = (const float*)d_in[1];   // gt_boxes (8,20,5) f32
  const float* anc = (const float*)d_in[4];   // anchors (1,200000,4) f32

  float* out         = (float*)d_out;
  float* out_labels  = out;                                  // [0, 1.6M)
  float* out_matches = out + (size_t)BATCH*NANCH;            // [1.6M, 3.2M)
  float* out_inds    = out + (size_t)2*BATCH*NANCH;          // [3.2M, 3.4M)
  float* out_anch    = out_inds + NANCH;                     // [3.4M, 4.2M)

  char* ws = (char*)d_ws;
  int*      gtmax = (int*)(ws + 0);             // 8*20*4 = 640 (pad 1KB)
  uint32_t* hist  = (uint32_t*)(ws + 1024);     // 8*2*16384*4 = 1 MB
  uint32_t* thr   = (uint32_t*)(ws + 1049600);  // 16*4 (pad 1KB)
  uint32_t* combo = (uint32_t*)(ws + 1050624);  // 1.6M*4 = 6.4 MB

  hipMemsetAsync(d_ws, 0, 1049600, stream);     // gtmax + hist

  k_gtmax <<<dim3(NBLKG, BATCH), 256, 0, stream>>>(gt, anc, gtmax);
  k_labels<<<dim3(NBLKL, BATCH), 256, 0, stream>>>(gt, anc, gtmax, combo,
                                                   out_matches, hist);
  k_sel   <<<BATCH, 256, 0, stream>>>(hist, thr);
  k_final <<<dim3(NBLKG, BATCH), 256, 0, stream>>>(combo, thr, anc,
                                                   out_labels, out_inds, out_anch);
}